// Round 5
// baseline (642.890 us; speedup 1.0000x reference)
//
#include <hip/hip_runtime.h>
#include <hip/hip_bf16.h>
#include <math.h>

#define IN_F    4096
#define OUT_F   4096
#define N_TOK   8192
#define GROUP   128
#define NSTAGE  4
#define NPAIRS  2048   // IN_F/2 pairs per stage
#define QMAXF   15.0
#define ROWS_PW 8      // rows per wave in build_w (amortizes routing precompute)

typedef unsigned short u16;
typedef __bf16 bf16x8 __attribute__((ext_vector_type(8)));
typedef float  f32x4  __attribute__((ext_vector_type(4)));

struct alignas(8) U16x4 { u16 x, y, z, w; };

__device__ __forceinline__ u16 f2bf(float f) {
    unsigned u = __float_as_uint(f);
    unsigned r = (u + 0x7fffu + ((u >> 16) & 1u)) >> 16;   // RNE
    return (u16)r;
}

__device__ __forceinline__ void gl_lds16(const void* g, void* l) {
    __builtin_amdgcn_global_load_lds(
        (const __attribute__((address_space(1))) void*)g,
        (__attribute__((address_space(3))) void*)l,
        16, 0, 0);
}

// cross-lane f64 pull through the LDS crossbar (conflict-free, no storage)
__device__ __forceinline__ double bperm64(int addr, double v) {
    long long u = __double_as_longlong(v);
    int lo = __builtin_amdgcn_ds_bpermute(addr, (int)u);
    int hi = __builtin_amdgcn_ds_bpermute(addr, (int)(u >> 32));
    return __longlong_as_double(((long long)(unsigned)lo) |
                                ((long long)hi << 32));
}
// desc = (src_lane<<1)|slot : fetch that lane's xi (slot 0) or xj (slot 1)
__device__ __forceinline__ double fetch2(double a, double b, int desc) {
    int addr = (desc >> 1) << 2;
    double va = bperm64(addr, a);
    double vb = bperm64(addr, b);
    return (desc & 1) ? vb : va;
}

// ---------------------------------------------------------------- tables ----
__global__ void make_tabs(const float* __restrict__ theta,
                          double* __restrict__ ctab, double* __restrict__ stab) {
    int i = blockIdx.x * 256 + threadIdx.x;
    if (i < NSTAGE * NPAIRS) {
        double t = (double)theta[i];
        ctab[i] = cos(t);
        stab[i] = sin(t);
    }
}

// ------------------------------------------------------------- transform ----
// One WAVE per (row-block, group). The chain (scale -> 4 rot -> qdq ->
// 4 inv-rot -> unscale) is block-diagonal per 128-elem group. REGISTER-
// RESIDENT dataflow: lane l always holds one PAIR (xi,xj) of the current
// stage; between stages values move via ds_bpermute (crossbar: no bank
// conflicts, no barriers, no LDS buffer). Routing is row-invariant:
// position tables pos_r[e] = (lane<<1)|slot of elem e in stage-r pair
// layout are built once per wave in LDS and folded into 16 per-lane
// descriptors, amortized over ROWS_PW rows. qdq is elementwise with
// group-uniform s/rzp -> applies in pair layout; inv stage 3 needs no
// movement (data already in stage-3 layout). f64 op sequence per element
// is identical to the previous (passing) version.
__global__ __launch_bounds__(256) void build_w(
    const float* __restrict__ weight, const float* __restrict__ cs,
    const float* __restrict__ qs, const float* __restrict__ qzp,
    const int* __restrict__ pairs,
    const double* __restrict__ ctab, const double* __restrict__ stab,
    u16* __restrict__ wb) {
    __shared__ int ptab[4][128];               // per-wave position table
    const int wave = threadIdx.x >> 6, l = threadIdx.x & 63;
    const int task = blockIdx.x * 4 + wave;    // (4096/ROWS_PW)*32 tasks
    const int ob = task >> 5, g = task & 31;
    const int o0 = ob * ROWS_PW;
    int* pt = ptab[wave];
    const int e0 = g * GROUP;

    // per-group constants, row-invariant
    const int2* prs = (const int2*)pairs;      // (i,j) pairs, 8B aligned
    int2   pp[NSTAGE];
    double c_[NSTAGE], s_[NSTAGE];
#pragma unroll
    for (int r = 0; r < NSTAGE; ++r) {
        pp[r] = prs[r * (IN_F / 2) + g * 64 + l];
        c_[r] = ctab[r * NPAIRS + g * 64 + l];
        s_[r] = stab[r * NPAIRS + g * 64 + l];
    }
    float2 cv = *(const float2*)(cs + e0 + 2 * l);
    const double cvx = (double)cv.x, cvy = (double)cv.y;
    const double rcx = 1.0 / cvx, rcy = 1.0 / cvy;

    // ---- routing precompute (once per wave-task) ----
    // pos_r: lane q owns elem i_r(q) in slot 0, j_r(q) in slot 1.
    int t1x, t1y, toutx, touty;    // from L0: pairs of stage1; canonical out
    int t2x, t2y, it0x, it0y;      // from L1: pairs of stage2; pairs of stage0
    int t3x, t3y, it1x, it1y;      // from L2: pairs of stage3; pairs of stage1
    int it2x, it2y;                // from L3: pairs of stage2
    pt[pp[0].x] = l << 1; pt[pp[0].y] = (l << 1) | 1;
    __builtin_amdgcn_wave_barrier();
    t1x = pt[pp[1].x]; t1y = pt[pp[1].y];
    toutx = pt[2 * l]; touty = pt[2 * l + 1];
    __builtin_amdgcn_wave_barrier();
    pt[pp[1].x] = l << 1; pt[pp[1].y] = (l << 1) | 1;
    __builtin_amdgcn_wave_barrier();
    t2x = pt[pp[2].x]; t2y = pt[pp[2].y];
    it0x = pt[pp[0].x]; it0y = pt[pp[0].y];
    __builtin_amdgcn_wave_barrier();
    pt[pp[2].x] = l << 1; pt[pp[2].y] = (l << 1) | 1;
    __builtin_amdgcn_wave_barrier();
    t3x = pt[pp[3].x]; t3y = pt[pp[3].y];
    it1x = pt[pp[1].x]; it1y = pt[pp[1].y];
    __builtin_amdgcn_wave_barrier();
    pt[pp[3].x] = l << 1; pt[pp[3].y] = (l << 1) | 1;
    __builtin_amdgcn_wave_barrier();
    it2x = pt[pp[2].x]; it2y = pt[pp[2].y];

#define TRANS(dx, dy) do {                                                     \
        double nx_ = fetch2(xi, xj, dx);                                       \
        double ny_ = fetch2(xi, xj, dy);                                       \
        xi = nx_; xj = ny_;                                                    \
    } while (0)
#define ROT_F(r) do {                                                          \
        double t_ = xi * c_[r] + xj * s_[r];                                   \
        xj = -xi * s_[r] + xj * c_[r];                                         \
        xi = t_;                                                               \
    } while (0)
#define ROT_I(r) do {                                                          \
        double t_ = xi * c_[r] - xj * s_[r];                                   \
        xj = xi * s_[r] + xj * c_[r];                                          \
        xi = t_;                                                               \
    } while (0)

    for (int o = o0; o < o0 + ROWS_PW; ++o) {
        float2 wv = *(const float2*)(weight + (size_t)o * IN_F + e0 + 2 * l);
        double v0 = (double)wv.x * cvx;        // canonical elems 2l, 2l+1
        double v1 = (double)wv.y * cvy;
        // canonical -> stage-0 pairs (pos_canon[e] = e)
        double xi = fetch2(v0, v1, pp[0].x);
        double xj = fetch2(v0, v1, pp[0].y);
        ROT_F(0);
        TRANS(t1x, t1y); ROT_F(1);
        TRANS(t2x, t2y); ROT_F(2);
        TRANS(t3x, t3y); ROT_F(3);

        // group quant-dequant (elementwise, group-uniform consts)
        {
            double sc  = fmin(fmax((double)qs[o * 32 + g], 1e-5), 1e5);
            double rzp = fmin(fmax(-rint((double)qzp[o * 32 + g]), 0.0), QMAXF);
            double inv = 1.0 / sc;
            xi = (fmin(fmax(rint(xi * inv) + rzp, 0.0), QMAXF) - rzp) * sc;
            xj = (fmin(fmax(rint(xj * inv) + rzp, 0.0), QMAXF) - rzp) * sc;
        }

        ROT_I(3);                              // in place: already L3 layout
        TRANS(it2x, it2y); ROT_I(2);
        TRANS(it1x, it1y); ROT_I(1);
        TRANS(it0x, it0y); ROT_I(0);
        // L0 -> canonical for the store
        double r0 = fetch2(xi, xj, toutx);
        double r1 = fetch2(xi, xj, touty);
        unsigned lo = f2bf((float)(r0 * rcx));
        unsigned hi = f2bf((float)(r1 * rcy));
        *(unsigned*)(wb + (size_t)o * IN_F + e0 + 2 * l) = lo | (hi << 16);
    }
#undef TRANS
#undef ROT_F
#undef ROT_I
}

// ----------------------------------------------------------------- cast x ---
__global__ void cast_x(const float* __restrict__ x, u16* __restrict__ xb) {
    size_t i = ((size_t)blockIdx.x * 256 + threadIdx.x) * 4;
    float4 v = *(const float4*)(x + i);
    U16x4 o;
    o.x = f2bf(v.x); o.y = f2bf(v.y); o.z = f2bf(v.z); o.w = f2bf(v.w);
    *(U16x4*)(xb + i) = o;
}

// ------------------------------------------------------------------ GEMM ----
// C[m,n] = sum_k A[m,k] * B[n,k] + bias[n]   (A: M x K, B: N x K, both bf16)
//
// R1 known-good structure (measured 299-300 us, MfmaUtil ~41): 256x256
// tile, 512 thr / 8 waves (2M x 4N, each 128x64), BK=32 sub-tiles in a
// 4-deep LDS ring (128 KiB). Counted-vmcnt pipeline: main loop NEVER drains
// vmcnt to 0 -- each iteration waits vmcnt(8) (retires only loads issued 3
// sub-tiles earlier), raw s_barrier (no compiler vmcnt(0) drain), then
// issues the next slot's 4 global_load_lds. Tail drains 8 -> 4 -> 0.
// LDS chunk-XOR swizzle via pre-swizzled global source (gl_lds writes
// linearly): quarter-wave ds_read_b128 is 2-way per bank = free (m136;
// measured 0 conflicts).
__global__ __launch_bounds__(512, 2) void gemm_bt(
    const u16* __restrict__ A, const u16* __restrict__ B,
    const float* __restrict__ bias, float* __restrict__ C) {
    constexpr int K = IN_F;
    constexpr int N = OUT_F;
    constexpr int NS = K / 32;                       // 128 sub-tiles
    __shared__ __align__(16) u16 As[4][256 * 32];    // 64 KB
    __shared__ __align__(16) u16 Bs[4][256 * 32];    // 64 KB

    const int tid  = threadIdx.x;
    const int wave = tid >> 6, lane = tid & 63;
    const int lrow = lane & 15, lq = lane >> 4;
    const int wm = wave >> 2, wn = wave & 3;         // 2x4 wave grid

    // XCD-bijective swizzle: 512 wgs, 8 XCDs. Each XCD gets one nt-pair
    // (4 MB of B panels -> L2-resident) across all 32 mt.
    const int wg = (blockIdx.x & 7) * 64 + (blockIdx.x >> 3);
    const int mt = wg & 31, nt = wg >> 5;
    const int m0 = mt * 256, n0 = nt * 256;

    // staging: 512 thr x 16B = 8 KB/round = 128 rows; 2 rounds per operand.
    // LDS dest is linear (gl_lds: wave base + lane*16); global src carries
    // the chunk swizzle: LDS chunk lc of row r holds global chunk lc^((r>>1)&3).
    const int srow = tid >> 2;                              // 0..127
    const int gch  = (tid & 3) ^ ((tid >> 3) & 3);          // swizzled source chunk
    const u16* pA0 = A + (size_t)(m0 + srow) * K + gch * 8;
    const u16* pA1 = pA0 + (size_t)128 * K;
    const u16* pB0 = B + (size_t)(n0 + srow) * K + gch * 8;
    const u16* pB1 = pB0 + (size_t)128 * K;

#define STAGE(slot, s) do {                                         \
        const int ko_ = (s) * 32;                                   \
        gl_lds16(pA0 + ko_, &As[slot][wave * 512]);                 \
        gl_lds16(pA1 + ko_, &As[slot][4096 + wave * 512]);          \
        gl_lds16(pB0 + ko_, &Bs[slot][wave * 512]);                 \
        gl_lds16(pB1 + ko_, &Bs[slot][4096 + wave * 512]);          \
    } while (0)

    f32x4 acc[8][4];
#pragma unroll
    for (int i = 0; i < 8; ++i)
#pragma unroll
        for (int j = 0; j < 4; ++j) acc[i][j] = (f32x4){0.f, 0.f, 0.f, 0.f};

    // prologue: fill 3 ring slots (12 loads in flight)
    STAGE(0, 0); STAGE(1, 1); STAGE(2, 2);

    // Per iteration: wait only for sub-tile s (issued 3 iters ago), barrier,
    // read frags, issue sub-tile s+3 into the slot everyone finished reading
    // last iteration (barrier guarantees), MFMA under setprio(1).
#define BODY(s, VMSTR, DO_STAGE) do {                                          \
        asm volatile("s_waitcnt " VMSTR);                                      \
        __builtin_amdgcn_s_barrier();                                          \
        asm volatile("" ::: "memory");                                         \
        const u16* as_ = As[(s) & 3];                                          \
        const u16* bs_ = Bs[(s) & 3];                                          \
        bf16x8 af[8], bf[4];                                                   \
        _Pragma("unroll")                                                      \
        for (int mi = 0; mi < 8; ++mi) {                                       \
            int ar = wm * 128 + mi * 16 + lrow;                                \
            af[mi] = *(const bf16x8*)&as_[ar * 32 +                            \
                                          (((lq ^ (ar >> 1)) & 3) << 3)];      \
        }                                                                      \
        _Pragma("unroll")                                                      \
        for (int nj = 0; nj < 4; ++nj) {                                       \
            int br = wn * 64 + nj * 16 + lrow;                                 \
            bf[nj] = *(const bf16x8*)&bs_[br * 32 +                            \
                                          (((lq ^ (br >> 1)) & 3) << 3)];      \
        }                                                                      \
        if (DO_STAGE) STAGE(((s) + 3) & 3, (s) + 3);                           \
        __builtin_amdgcn_s_setprio(1);                                         \
        _Pragma("unroll")                                                      \
        for (int mi = 0; mi < 8; ++mi)                                         \
            _Pragma("unroll")                                                  \
            for (int nj = 0; nj < 4; ++nj)                                     \
                acc[mi][nj] = __builtin_amdgcn_mfma_f32_16x16x32_bf16(         \
                    af[mi], bf[nj], acc[mi][nj], 0, 0, 0);                     \
        __builtin_amdgcn_s_setprio(0);                                         \
        asm volatile("" ::: "memory");                                         \
    } while (0)

    for (int s = 0; s < NS - 3; ++s)
        BODY(s, "vmcnt(8)", 1);
    // tail: drain 8 -> 4 -> 0
    BODY(NS - 3, "vmcnt(8)", 0);
    BODY(NS - 2, "vmcnt(4)", 0);
    BODY(NS - 1, "vmcnt(0)", 0);

#undef BODY
#undef STAGE

    // epilogue: C/D layout col = lane&15, row = (lane>>4)*4 + reg
#pragma unroll
    for (int mi = 0; mi < 8; ++mi) {
        int rb = m0 + wm * 128 + mi * 16 + lq * 4;
#pragma unroll
        for (int nj = 0; nj < 4; ++nj) {
            int col = n0 + wn * 64 + nj * 16 + lrow;
            float bv = bias[col];
#pragma unroll
            for (int r = 0; r < 4; ++r)
                C[(size_t)(rb + r) * N + col] = acc[mi][nj][r] + bv;
        }
    }
}

// ---------------------------------------------------------------- launch ----
extern "C" void kernel_launch(void* const* d_in, const int* in_sizes, int n_in,
                              void* d_out, int out_size, void* d_ws, size_t ws_size,
                              hipStream_t stream) {
    const float* x    = (const float*)d_in[0];
    const float* w    = (const float*)d_in[1];
    const float* bias = (const float*)d_in[2];
    const float* cs   = (const float*)d_in[3];
    const float* th   = (const float*)d_in[4];
    const float* qs   = (const float*)d_in[5];
    const float* qzp  = (const float*)d_in[6];
    const int*   pr   = (const int*)d_in[7];
    float* out = (float*)d_out;

    char* ws = (char*)d_ws;
    double* ctab = (double*)ws;                                  // 64 KB
    double* stab = (double*)(ws + 65536);                        // 64 KB
    u16*    xb   = (u16*)(ws + 131072);                          // 64 MB
    u16*    wb   = (u16*)(ws + 131072 + (size_t)N_TOK * IN_F * 2);  // 32 MB

    hipLaunchKernelGGL(make_tabs, dim3((NSTAGE * NPAIRS + 255) / 256), dim3(256),
                       0, stream, th, ctab, stab);
    hipLaunchKernelGGL(build_w, dim3(OUT_F / ROWS_PW * 32 / 4), dim3(256),
                       0, stream, w, cs, qs, qzp, pr, ctab, stab, wb);
    hipLaunchKernelGGL(cast_x, dim3(N_TOK * IN_F / 4 / 256), dim3(256), 0, stream,
                       x, xb);
    hipLaunchKernelGGL(gemm_bt, dim3((N_TOK / 256) * (OUT_F / 256)), dim3(512),
                       0, stream, xb, wb, bias, out);
}